// Round 5
// baseline (1652.658 us; speedup 1.0000x reference)
//
#include <hip/hip_runtime.h>
#include <hip/hip_bf16.h>
#include <stdint.h>

typedef __attribute__((ext_vector_type(8))) short short8;
typedef __attribute__((ext_vector_type(4))) float floatx4;
using bf16_t = __hip_bfloat16;

#define K_DIM 4096
#define N_DIM 11008
#define NQ_DIM 1376
#define BK 32
#define NSTEPS 128
#define BM 256
#define BN 128

__device__ __forceinline__ uint32_t pack_bf16x2(float lo, float hi) {
    union { __hip_bfloat162 h2; uint32_t u; } cv;
    cv.h2 = __hip_bfloat162(__float2bfloat16(lo), __float2bfloat16(hi));
    return cv.u;
}

// ---- pass 0: x f32 -> bf16 into workspace ----
__global__ __launch_bounds__(256)
void cvt_x(const float* __restrict__ x, unsigned short* __restrict__ xb, int n8) {
    int i = blockIdx.x * 256 + threadIdx.x;
    const int stride = gridDim.x * 256;
    for (; i < n8; i += stride) {
        floatx4 a = *(const floatx4*)(x + (size_t)i * 8);
        floatx4 b = *(const floatx4*)(x + (size_t)i * 8 + 4);
        union { short8 v; uint32_t u[4]; } o;
        o.u[0] = pack_bf16x2(a[0], a[1]);
        o.u[1] = pack_bf16x2(a[2], a[3]);
        o.u[2] = pack_bf16x2(b[0], b[1]);
        o.u[3] = pack_bf16x2(b[2], b[3]);
        *(short8*)(xb + (size_t)i * 8) = o.v;
    }
}

// ---- fused AWQ GEMM: BM=256 x BN=128, BK=32, 512 threads (8 waves, 4M x 2N) ----
// LDS: [0,16384)  A tile: row-major [256 rows][32 k] bf16, row stride 64 B
//      [16384,24576) B tile: 16B blocks blk = kb*128 + col, swizzled blk ^= (blk>>3)&7
template <bool PRECVT>
__global__ __launch_bounds__(512, 2)
void awq_gemm2(const float* __restrict__ xf,
               const unsigned short* __restrict__ xb,
               const int* __restrict__ qweight,
               const int* __restrict__ qzeros,
               const float* __restrict__ scales,
               const float* __restrict__ bias,
               float* __restrict__ out)
{
    __shared__ char lds[24576] __attribute__((aligned(128)));

    const int tid  = threadIdx.x;
    const int lane = tid & 63;
    const int wid  = tid >> 6;

    const int n0 = blockIdx.x * BN;
    const int m0 = blockIdx.y * BM;

    // ---- A staging setup ----
    // PRECVT: per wave, 2 x global_load_lds(16B): issue s covers rows s*128 + wid*16 + (lane>>2),
    //         k-quarter lane&3; LDS dest lane-linear == row*64 + (lane&3)*16.
    const unsigned short* agl0 = xb + (size_t)(m0 + wid * 16 + (lane >> 2)) * K_DIM + (lane & 3) * 8;
    const unsigned short* agl1 = agl0 + (size_t)128 * K_DIM;
    char* aldsbase0 = &lds[(wid * 16) * 64];
    char* aldsbase1 = &lds[(128 + wid * 16) * 64];
    // fallback: thread owns one row-half: row = tid>>1, half = tid&1 (16 f32 -> 16 bf16)
    const float* aptr = xf + (size_t)(m0 + (tid >> 1)) * K_DIM + (tid & 1) * 16;
    const int awr = (tid >> 1) * 64 + (tid & 1) * 32;

    // ---- B dequant mapping: thread owns 1 k-pair x 4 cols ----
    const int c4      = tid & 31;        // col quad: cols c4*4 .. +3
    const int kp      = tid >> 5;        // 0..15
    const int k_local = kp * 2;
    const int kb_w    = k_local >> 3;
    const int k8      = k_local & 7;     // even
    const int wcol    = blockIdx.x * 16 + (c4 >> 1);
    const int* qcol = qweight + wcol;
    const int* zcol = qzeros + wcol;
    const float* scol = scales + n0 + c4 * 4;
    int sh[4], bwr[4];
#pragma unroll
    for (int dj = 0; dj < 4; ++dj) {
        const int j_oct = (c4 & 1) * 4 + dj;
        sh[dj] = ((j_oct & 1) ? 16 : 0) + (j_oct >> 1) * 4;   // AWQ inverse order
        int blk = kb_w * 128 + c4 * 4 + dj;
        blk ^= (blk >> 3) & 7;
        bwr[dj] = 16384 + blk * 16 + k8 * 2;
    }

    // ---- fragment offsets ----
    const int wm = (wid >> 1) * 64;
    const int wn = (wid & 1) * 64;
    const int lm = lane & 15;
    const int kb_l = lane >> 4;
    const int aoff = (wm + lm) * 64 + kb_l * 16;     // + i*16*64
    int boff[4];
#pragma unroll
    for (int j = 0; j < 4; ++j) {
        int blk = kb_l * 128 + wn + j * 16 + lm;
        blk ^= (blk >> 3) & 7;
        boff[j] = 16384 + blk * 16;
    }

    floatx4 acc[4][4];
#pragma unroll
    for (int i = 0; i < 4; ++i)
#pragma unroll
        for (int j = 0; j < 4; ++j)
            acc[i][j] = (floatx4){0.f, 0.f, 0.f, 0.f};

    float s_f[4], mc[4];

    uint32_t q0 = (uint32_t)qcol[(size_t)k_local * NQ_DIM];
    uint32_t q1 = (uint32_t)qcol[(size_t)(k_local + 1) * NQ_DIM];

    for (int ks = 0; ks < NSTEPS; ++ks) {
        const int k0 = ks * BK;

        // ---- A stage ----
        floatx4 av[4];
        if constexpr (PRECVT) {
            __builtin_amdgcn_global_load_lds(
                (const __attribute__((address_space(1))) void*)(agl0 + k0),
                (__attribute__((address_space(3))) void*)aldsbase0, 16, 0, 0);
            __builtin_amdgcn_global_load_lds(
                (const __attribute__((address_space(1))) void*)(agl1 + k0),
                (__attribute__((address_space(3))) void*)aldsbase1, 16, 0, 0);
        } else {
#pragma unroll
            for (int p = 0; p < 4; ++p)
                av[p] = *(const floatx4*)(aptr + k0 + p * 4);
        }

        // ---- group boundary: refresh scale / fused zero term (4 cols) ----
        if ((ks & 3) == 0) {
            const int g = ks >> 2;
            const uint32_t zw = (uint32_t)zcol[(size_t)g * NQ_DIM];
            const floatx4 sv = *(const floatx4*)(scol + (size_t)g * N_DIM);
#pragma unroll
            for (int dj = 0; dj < 4; ++dj) {
                const float z = (float)((zw >> sh[dj]) & 0xFu);
                s_f[dj] = sv[dj];
                mc[dj]  = -(z + 128.0f) * sv[dj];
            }
        }

        // ---- prefetch next step's q words ----
        uint32_t qn0 = 0, qn1 = 0;
        if (ks + 1 < NSTEPS) {
            qn0 = (uint32_t)qcol[(size_t)(k0 + BK + k_local) * NQ_DIM];
            qn1 = (uint32_t)qcol[(size_t)(k0 + BK + k_local + 1) * NQ_DIM];
        }

        if constexpr (!PRECVT) {
            union { short8 v; uint32_t u[4]; } o0, o1;
            o0.u[0] = pack_bf16x2(av[0][0], av[0][1]);
            o0.u[1] = pack_bf16x2(av[0][2], av[0][3]);
            o0.u[2] = pack_bf16x2(av[1][0], av[1][1]);
            o0.u[3] = pack_bf16x2(av[1][2], av[1][3]);
            o1.u[0] = pack_bf16x2(av[2][0], av[2][1]);
            o1.u[1] = pack_bf16x2(av[2][2], av[2][3]);
            o1.u[2] = pack_bf16x2(av[3][0], av[3][1]);
            o1.u[3] = pack_bf16x2(av[3][2], av[3][3]);
            *(short8*)&lds[awr]      = o0.v;
            *(short8*)&lds[awr + 16] = o1.v;
        }

        // ---- B dequant: 4 cols x 1 k-pair ----
#pragma unroll
        for (int dj = 0; dj < 4; ++dj) {
            const int s4 = sh[dj];
            uint32_t t0 = (s4 <= 16) ? (q0 << (16 - s4)) : (q0 >> (s4 - 16));
            uint32_t t1 = (s4 <= 16) ? (q1 << (16 - s4)) : (q1 >> (s4 - 16));
            float f0 = __uint_as_float((t0 & 0x000F0000u) | 0x43000000u);  // 128 + nib
            float f1 = __uint_as_float((t1 & 0x000F0000u) | 0x43000000u);
            float w0 = fmaf(f0, s_f[dj], mc[dj]);
            float w1 = fmaf(f1, s_f[dj], mc[dj]);
            *(uint32_t*)&lds[bwr[dj]] = pack_bf16x2(w0, w1);
        }

        __syncthreads();

        short8 af[4], bfr[4];
#pragma unroll
        for (int i = 0; i < 4; ++i) af[i] = *(const short8*)&lds[aoff + i * 1024];
#pragma unroll
        for (int j = 0; j < 4; ++j) bfr[j] = *(const short8*)&lds[boff[j]];

#pragma unroll
        for (int i = 0; i < 4; ++i)
#pragma unroll
            for (int j = 0; j < 4; ++j)
                acc[i][j] = __builtin_amdgcn_mfma_f32_16x16x32_bf16(af[i], bfr[j], acc[i][j], 0, 0, 0);

        __syncthreads();
        q0 = qn0; q1 = qn1;
    }

    // ---- epilogue: C/D col = lane&15, row = (lane>>4)*4 + r ----
    const int colb = n0 + wn + lm;
    const int rowb = m0 + wm + (kb_l << 2);
#pragma unroll
    for (int j = 0; j < 4; ++j) {
        const int col = colb + j * 16;
        const float bias_f = bias[col];
#pragma unroll
        for (int i = 0; i < 4; ++i) {
            const int row = rowb + i * 16;
#pragma unroll
            for (int r = 0; r < 4; ++r) {
                out[(size_t)(row + r) * N_DIM + col] = acc[i][j][r] + bias_f;
            }
        }
    }
}

extern "C" void kernel_launch(void* const* d_in, const int* in_sizes, int n_in,
                              void* d_out, int out_size, void* d_ws, size_t ws_size,
                              hipStream_t stream) {
    const float* x    = (const float*)d_in[0];
    const int* qw     = (const int*)d_in[1];
    const int* qz     = (const int*)d_in[2];
    const float* sc   = (const float*)d_in[3];
    const float* bi   = (const float*)d_in[4];
    float* out        = (float*)d_out;

    const int M = in_sizes[0] / K_DIM;                 // 8192
    const size_t xb_bytes = (size_t)M * K_DIM * 2;
    dim3 grid(N_DIM / BN, M / BM);                     // (86, 32)

    if (ws_size >= xb_bytes) {
        unsigned short* xb = (unsigned short*)d_ws;
        const int n8 = (int)((size_t)M * K_DIM / 8);
        cvt_x<<<2048, 256, 0, stream>>>(x, xb, n8);
        awq_gemm2<true><<<grid, 512, 0, stream>>>(x, xb, qw, qz, sc, bi, out);
    } else {
        awq_gemm2<false><<<grid, 512, 0, stream>>>(x, nullptr, qw, qz, sc, bi, out);
    }
}

// Round 6
// 1437.037 us; speedup vs baseline: 1.1500x; 1.1500x over previous
//
#include <hip/hip_runtime.h>
#include <hip/hip_bf16.h>
#include <stdint.h>

typedef __attribute__((ext_vector_type(8))) short short8;
typedef __attribute__((ext_vector_type(4))) float floatx4;

#define K_DIM 4096
#define N_DIM 11008
#define NQ_DIM 1376
#define BK 32
#define NSTEPS 128
#define BM 256
#define BN 128
#define ABUF 16384
#define BBASE 32768
#define BBUF 8192

__device__ __forceinline__ uint32_t pack_bf16x2(float lo, float hi) {
    union { __hip_bfloat162 h2; uint32_t u; } cv;
    cv.h2 = __hip_bfloat162(__float2bfloat16(lo), __float2bfloat16(hi));
    return cv.u;
}

// ---- pass 0: x f32 -> bf16 into workspace ----
__global__ __launch_bounds__(256)
void cvt_x(const float* __restrict__ x, unsigned short* __restrict__ xb, int n8) {
    int i = blockIdx.x * 256 + threadIdx.x;
    const int stride = gridDim.x * 256;
    for (; i < n8; i += stride) {
        floatx4 a = *(const floatx4*)(x + (size_t)i * 8);
        floatx4 b = *(const floatx4*)(x + (size_t)i * 8 + 4);
        union { short8 v; uint32_t u[4]; } o;
        o.u[0] = pack_bf16x2(a[0], a[1]);
        o.u[1] = pack_bf16x2(a[2], a[3]);
        o.u[2] = pack_bf16x2(b[0], b[1]);
        o.u[3] = pack_bf16x2(b[2], b[3]);
        *(short8*)(xb + (size_t)i * 8) = o.v;
    }
}

// ---- fused AWQ GEMM: BM=256 x BN=128, BK=32, 512 threads (8 waves, 4M x 2N) ----
// LDS (49152 B): A bufs at 0 / 16384  (row-major [256][32] bf16, 64 B rows)
//                B bufs at 32768 / 40960 (16B blocks blk = kb*128 + col, blk ^= (blk>>3)&7)
// Pipeline: 2-phase double-buffer, ONE barrier per K-step.
template <bool PRECVT>
__global__ __launch_bounds__(512, 2)
void awq_gemm3(const float* __restrict__ xf,
               const unsigned short* __restrict__ xb,
               const int* __restrict__ qweight,
               const int* __restrict__ qzeros,
               const float* __restrict__ scales,
               const float* __restrict__ bias,
               float* __restrict__ out)
{
    __shared__ char lds[49152] __attribute__((aligned(128)));

    const int tid  = threadIdx.x;
    const int lane = tid & 63;
    const int wid  = tid >> 6;

    const int n0 = blockIdx.x * BN;
    const int m0 = blockIdx.y * BM;

    // ---- A staging setup ----
    const unsigned short* agl0 = xb + (size_t)(m0 + wid * 16 + (lane >> 2)) * K_DIM + (lane & 3) * 8;
    const unsigned short* agl1 = agl0 + (size_t)128 * K_DIM;
    const int aldsoff0 = (wid * 16) * 64;          // + implicit lane*16 by HW
    const int aldsoff1 = (128 + wid * 16) * 64;
    const float* aptr = xf + (size_t)(m0 + (tid >> 1)) * K_DIM + (tid & 1) * 16;  // fallback
    const int awr = (tid >> 1) * 64 + (tid & 1) * 32;

    // ---- B dequant mapping: thread owns 1 k-pair x 4 cols (verified R5) ----
    const int c4      = tid & 31;
    const int k_local = (tid >> 5) * 2;
    const int kb_w    = k_local >> 3;
    const int k8      = k_local & 7;
    const int wcol    = blockIdx.x * 16 + (c4 >> 1);
    const int* qcol = qweight + wcol;
    const int* zcol = qzeros + wcol;
    const float* scol = scales + n0 + c4 * 4;
    int sh[4], bwr[4];
#pragma unroll
    for (int dj = 0; dj < 4; ++dj) {
        const int j_oct = (c4 & 1) * 4 + dj;
        sh[dj] = ((j_oct & 1) ? 16 : 0) + (j_oct >> 1) * 4;
        int blk = kb_w * 128 + c4 * 4 + dj;
        blk ^= (blk >> 3) & 7;
        bwr[dj] = blk * 16 + k8 * 2;               // offset within a B buf
    }

    // ---- fragment offsets (within-buf) ----
    const int wm = (wid >> 1) * 64;
    const int wn = (wid & 1) * 64;
    const int lm = lane & 15;
    const int kb_l = lane >> 4;
    const int aoff = (wm + lm) * 64 + kb_l * 16;
    int boff[4];
#pragma unroll
    for (int j = 0; j < 4; ++j) {
        int blk = kb_l * 128 + wn + j * 16 + lm;
        blk ^= (blk >> 3) & 7;
        boff[j] = blk * 16;
    }

    floatx4 acc[4][4];
#pragma unroll
    for (int i = 0; i < 4; ++i)
#pragma unroll
        for (int j = 0; j < 4; ++j)
            acc[i][j] = (floatx4){0.f, 0.f, 0.f, 0.f};

    float s_f[4], mc[4];
    uint32_t q0, q1;

    auto stage_a = [&](int t, int abase) {
        if constexpr (PRECVT) {
            __builtin_amdgcn_global_load_lds(
                (const __attribute__((address_space(1))) void*)(agl0 + (size_t)t * BK),
                (__attribute__((address_space(3))) void*)(&lds[abase + aldsoff0]), 16, 0, 0);
            __builtin_amdgcn_global_load_lds(
                (const __attribute__((address_space(1))) void*)(agl1 + (size_t)t * BK),
                (__attribute__((address_space(3))) void*)(&lds[abase + aldsoff1]), 16, 0, 0);
        } else {
            floatx4 av[4];
#pragma unroll
            for (int p = 0; p < 4; ++p)
                av[p] = *(const floatx4*)(aptr + t * BK + p * 4);
            union { short8 v; uint32_t u[4]; } o0, o1;
            o0.u[0] = pack_bf16x2(av[0][0], av[0][1]);
            o0.u[1] = pack_bf16x2(av[0][2], av[0][3]);
            o0.u[2] = pack_bf16x2(av[1][0], av[1][1]);
            o0.u[3] = pack_bf16x2(av[1][2], av[1][3]);
            o1.u[0] = pack_bf16x2(av[2][0], av[2][1]);
            o1.u[1] = pack_bf16x2(av[2][2], av[2][3]);
            o1.u[2] = pack_bf16x2(av[3][0], av[3][1]);
            o1.u[3] = pack_bf16x2(av[3][2], av[3][3]);
            *(short8*)&lds[abase + awr]      = o0.v;
            *(short8*)&lds[abase + awr + 16] = o1.v;
        }
    };
    auto load_q = [&](int t) {
        const size_t kk = (size_t)t * BK + k_local;
        q0 = (uint32_t)qcol[kk * NQ_DIM];
        q1 = (uint32_t)qcol[(kk + 1) * NQ_DIM];
    };
    auto refresh = [&](int T) {
        const int g = T >> 2;
        const uint32_t zw = (uint32_t)zcol[(size_t)g * NQ_DIM];
        const floatx4 sv = *(const floatx4*)(scol + (size_t)g * N_DIM);
#pragma unroll
        for (int dj = 0; dj < 4; ++dj) {
            const float z = (float)((zw >> sh[dj]) & 0xFu);
            s_f[dj] = sv[dj];
            mc[dj]  = -(z + 128.0f) * sv[dj];
        }
    };
    auto deq_store = [&](int bbase) {
#pragma unroll
        for (int dj = 0; dj < 4; ++dj) {
            const int s4 = sh[dj];
            uint32_t t0 = (s4 <= 16) ? (q0 << (16 - s4)) : (q0 >> (s4 - 16));
            uint32_t t1 = (s4 <= 16) ? (q1 << (16 - s4)) : (q1 >> (s4 - 16));
            float f0 = __uint_as_float((t0 & 0x000F0000u) | 0x43000000u);  // 128 + nib
            float f1 = __uint_as_float((t1 & 0x000F0000u) | 0x43000000u);
            float w0 = fmaf(f0, s_f[dj], mc[dj]);
            float w1 = fmaf(f1, s_f[dj], mc[dj]);
            *(uint32_t*)&lds[bbase + bwr[dj]] = pack_bf16x2(w0, w1);
        }
    };

    // ---- prologue: stage tile 0, prefetch q(1) ----
    stage_a(0, 0);
    load_q(0);
    refresh(0);
    deq_store(BBASE);
    load_q(1);
    __syncthreads();

    int cur = 0;
    for (int t = 0; t < NSTEPS; ++t) {
        const int nxt = cur ^ 1;
        if (t + 1 < NSTEPS) {
            stage_a(t + 1, nxt * ABUF);            // async, drains at the barrier
            if (((t + 1) & 3) == 0) refresh(t + 1);
            deq_store(BBASE + nxt * BBUF);         // consumes q(t+1)
            if (t + 2 < NSTEPS) load_q(t + 2);     // refill q regs
        }

        const int ab = cur * ABUF;
        const int bb = BBASE + cur * BBUF;
        short8 af[4], bfr[4];
#pragma unroll
        for (int i = 0; i < 4; ++i) af[i] = *(const short8*)&lds[ab + aoff + i * 1024];
#pragma unroll
        for (int j = 0; j < 4; ++j) bfr[j] = *(const short8*)&lds[bb + boff[j]];

#pragma unroll
        for (int i = 0; i < 4; ++i)
#pragma unroll
            for (int j = 0; j < 4; ++j)
                acc[i][j] = __builtin_amdgcn_mfma_f32_16x16x32_bf16(af[i], bfr[j], acc[i][j], 0, 0, 0);

        if (t + 1 < NSTEPS) __syncthreads();
        cur = nxt;
    }

    // ---- epilogue: C/D col = lane&15, row = (lane>>4)*4 + r ----
    const int colb = n0 + wn + lm;
    const int rowb = m0 + wm + (kb_l << 2);
#pragma unroll
    for (int j = 0; j < 4; ++j) {
        const int col = colb + j * 16;
        const float bias_f = bias[col];
#pragma unroll
        for (int i = 0; i < 4; ++i) {
            const int row = rowb + i * 16;
#pragma unroll
            for (int r = 0; r < 4; ++r) {
                out[(size_t)(row + r) * N_DIM + col] = acc[i][j][r] + bias_f;
            }
        }
    }
}

extern "C" void kernel_launch(void* const* d_in, const int* in_sizes, int n_in,
                              void* d_out, int out_size, void* d_ws, size_t ws_size,
                              hipStream_t stream) {
    const float* x    = (const float*)d_in[0];
    const int* qw     = (const int*)d_in[1];
    const int* qz     = (const int*)d_in[2];
    const float* sc   = (const float*)d_in[3];
    const float* bi   = (const float*)d_in[4];
    float* out        = (float*)d_out;

    const int M = in_sizes[0] / K_DIM;                 // 8192
    const size_t xb_bytes = (size_t)M * K_DIM * 2;
    dim3 grid(N_DIM / BN, M / BM);                     // (86, 32)

    if (ws_size >= xb_bytes) {
        unsigned short* xb = (unsigned short*)d_ws;
        const int n8 = (int)((size_t)M * K_DIM / 8);
        cvt_x<<<2048, 256, 0, stream>>>(x, xb, n8);
        awq_gemm3<true><<<grid, 512, 0, stream>>>(x, xb, qw, qz, sc, bi, out);
    } else {
        awq_gemm3<false><<<grid, 512, 0, stream>>>(x, nullptr, qw, qz, sc, bi, out);
    }
}

// Round 7
// 1130.962 us; speedup vs baseline: 1.4613x; 1.2706x over previous
//
#include <hip/hip_runtime.h>
#include <hip/hip_bf16.h>
#include <stdint.h>

typedef __attribute__((ext_vector_type(8))) short short8;
typedef __attribute__((ext_vector_type(4))) float floatx4;

#define K_DIM 4096
#define N_DIM 11008
#define NQ_DIM 1376
#define BK 32
#define NSTEPS 128
#define BM 128
#define BN 128
#define ABUF 8192
#define BBASE 16384
#define BBUF 8192

__device__ __forceinline__ uint32_t pack_bf16x2(float lo, float hi) {
    union { __hip_bfloat162 h2; uint32_t u; } cv;
    cv.h2 = __hip_bfloat162(__float2bfloat16(lo), __float2bfloat16(hi));
    return cv.u;
}

// ---- pass 0: x f32 -> bf16 into workspace ----
__global__ __launch_bounds__(256)
void cvt_x(const float* __restrict__ x, unsigned short* __restrict__ xb, int n8) {
    int i = blockIdx.x * 256 + threadIdx.x;
    const int stride = gridDim.x * 256;
    for (; i < n8; i += stride) {
        floatx4 a = *(const floatx4*)(x + (size_t)i * 8);
        floatx4 b = *(const floatx4*)(x + (size_t)i * 8 + 4);
        union { short8 v; uint32_t u[4]; } o;
        o.u[0] = pack_bf16x2(a[0], a[1]);
        o.u[1] = pack_bf16x2(a[2], a[3]);
        o.u[2] = pack_bf16x2(b[0], b[1]);
        o.u[3] = pack_bf16x2(b[2], b[3]);
        *(short8*)(xb + (size_t)i * 8) = o.v;
    }
}

// ---- fused AWQ GEMM: BM=128 x BN=128, BK=32, 256 threads (4 waves, 2M x 2N) ----
// LDS (32768 B): A bufs at 0 / 8192   (row-major [128][32] bf16, 64 B rows)
//                B bufs at 16384 / 24576 (16B blocks blk = kb*128 + col, blk ^= (blk>>3)&7)
// Pipeline: 2-phase double-buffer, ONE barrier per K-step; 3 blocks/CU via launch_bounds(256,3).
template <bool PRECVT>
__global__ __launch_bounds__(256, 3)
void awq_gemm4(const float* __restrict__ xf,
               const unsigned short* __restrict__ xb,
               const int* __restrict__ qweight,
               const int* __restrict__ qzeros,
               const float* __restrict__ scales,
               const float* __restrict__ bias,
               float* __restrict__ out)
{
    __shared__ char lds[32768] __attribute__((aligned(128)));

    const int tid  = threadIdx.x;
    const int lane = tid & 63;
    const int wid  = tid >> 6;

    const int n0 = blockIdx.x * BN;
    const int m0 = blockIdx.y * BM;

    // ---- A staging setup (PRECVT): 2 x global_load_lds(16B) per thread ----
    // issue s: rows s*64 + wid*16 + (lane>>2), k-quarter lane&3; LDS dest lane-linear.
    const unsigned short* agl0 = xb + (size_t)(m0 + wid * 16 + (lane >> 2)) * K_DIM + (lane & 3) * 8;
    const unsigned short* agl1 = agl0 + (size_t)64 * K_DIM;
    const int aldsoff0 = wid * 1024;
    const int aldsoff1 = 4096 + wid * 1024;
    // fallback: thread owns one row-half (16 f32 -> 16 bf16)
    const float* aptr = xf + (size_t)(m0 + (tid >> 1)) * K_DIM + (tid & 1) * 16;
    const int awr = (tid >> 1) * 64 + (tid & 1) * 32;

    // ---- B dequant mapping (R4-verified): thread owns 1 k-pair x 8 cols ----
    const int nq      = tid & 15;        // packed-word column
    const int k_local = (tid >> 4) * 2;  // 0..30 even
    const int k8      = k_local & 7;
    const int nq7     = nq & 7;
    const int* qcol = qweight + blockIdx.x * 16 + nq;
    const int* zcol = qzeros  + blockIdx.x * 16 + nq;
    const float* scol = scales + n0 + nq * 8;
    const int bwr_base = ((k_local >> 3) * 128 + nq * 8) * 16 + k8 * 2;   // within-buf

    // ---- fragment offsets (within-buf) ----
    const int wm = (wid >> 1) * 64;
    const int wn = (wid & 1) * 64;
    const int lm = lane & 15;
    const int kb_l = lane >> 4;
    const int aoff = (wm + lm) * 64 + kb_l * 16;
    int boff[4];
#pragma unroll
    for (int j = 0; j < 4; ++j) {
        int blk = kb_l * 128 + wn + j * 16 + lm;
        blk ^= (blk >> 3) & 7;
        boff[j] = blk * 16;
    }

    floatx4 acc[4][4];
#pragma unroll
    for (int i = 0; i < 4; ++i)
#pragma unroll
        for (int j = 0; j < 4; ++j)
            acc[i][j] = (floatx4){0.f, 0.f, 0.f, 0.f};

    float s_f[8], mc[8];
    uint32_t q0, q1;

    auto stage_a = [&](int t, int abase) {
        if constexpr (PRECVT) {
            __builtin_amdgcn_global_load_lds(
                (const __attribute__((address_space(1))) void*)(agl0 + (size_t)t * BK),
                (__attribute__((address_space(3))) void*)(&lds[abase + aldsoff0]), 16, 0, 0);
            __builtin_amdgcn_global_load_lds(
                (const __attribute__((address_space(1))) void*)(agl1 + (size_t)t * BK),
                (__attribute__((address_space(3))) void*)(&lds[abase + aldsoff1]), 16, 0, 0);
        } else {
            floatx4 av[4];
#pragma unroll
            for (int p = 0; p < 4; ++p)
                av[p] = *(const floatx4*)(aptr + t * BK + p * 4);
            union { short8 v; uint32_t u[4]; } o0, o1;
            o0.u[0] = pack_bf16x2(av[0][0], av[0][1]);
            o0.u[1] = pack_bf16x2(av[0][2], av[0][3]);
            o0.u[2] = pack_bf16x2(av[1][0], av[1][1]);
            o0.u[3] = pack_bf16x2(av[1][2], av[1][3]);
            o1.u[0] = pack_bf16x2(av[2][0], av[2][1]);
            o1.u[1] = pack_bf16x2(av[2][2], av[2][3]);
            o1.u[2] = pack_bf16x2(av[3][0], av[3][1]);
            o1.u[3] = pack_bf16x2(av[3][2], av[3][3]);
            *(short8*)&lds[abase + awr]      = o0.v;
            *(short8*)&lds[abase + awr + 16] = o1.v;
        }
    };
    auto load_q = [&](int t) {
        const size_t kk = (size_t)t * BK + k_local;
        q0 = (uint32_t)qcol[kk * NQ_DIM];
        q1 = (uint32_t)qcol[(kk + 1) * NQ_DIM];
    };
    auto refresh = [&](int T) {
        const int g = T >> 2;
        const uint32_t zw = (uint32_t)zcol[(size_t)g * NQ_DIM];
        const floatx4 sv0 = *(const floatx4*)(scol + (size_t)g * N_DIM);
        const floatx4 sv1 = *(const floatx4*)(scol + (size_t)g * N_DIM + 4);
#pragma unroll
        for (int j = 0; j < 8; ++j) {
            const int sh = ((j & 1) ? 16 : 0) + (j >> 1) * 4;   // AWQ inverse order
            const float s = (j < 4) ? sv0[j] : sv1[j - 4];
            const float z = (float)((zw >> sh) & 0xFu);
            s_f[j] = s;
            mc[j]  = -(z + 128.0f) * s;
        }
    };
    auto deq_store = [&](int bbase) {
#pragma unroll
        for (int j = 0; j < 8; ++j) {
            const int sh = ((j & 1) ? 16 : 0) + (j >> 1) * 4;
            uint32_t t0 = (sh <= 16) ? (q0 << (16 - sh)) : (q0 >> (sh - 16));
            uint32_t t1 = (sh <= 16) ? (q1 << (16 - sh)) : (q1 >> (sh - 16));
            float f0 = __uint_as_float((t0 & 0x000F0000u) | 0x43000000u);  // 128 + nib
            float f1 = __uint_as_float((t1 & 0x000F0000u) | 0x43000000u);
            float w0 = fmaf(f0, s_f[j], mc[j]);
            float w1 = fmaf(f1, s_f[j], mc[j]);
            *(uint32_t*)&lds[bbase + bwr_base + ((j ^ nq7) * 16)] = pack_bf16x2(w0, w1);
        }
    };

    // ---- prologue: stage tile 0, prefetch q(1) ----
    stage_a(0, 0);
    load_q(0);
    refresh(0);
    deq_store(BBASE);
    load_q(1);
    __syncthreads();

    int cur = 0;
    for (int t = 0; t < NSTEPS; ++t) {
        const int nxt = cur ^ 1;
        if (t + 1 < NSTEPS) {
            stage_a(t + 1, nxt * ABUF);            // async, drains at the barrier
            if (((t + 1) & 3) == 0) refresh(t + 1);
            deq_store(BBASE + nxt * BBUF);         // consumes q(t+1)
            if (t + 2 < NSTEPS) load_q(t + 2);     // refill q regs
        }

        const int ab = cur * ABUF;
        const int bb = BBASE + cur * BBUF;
        short8 af[4], bfr[4];
#pragma unroll
        for (int i = 0; i < 4; ++i) af[i] = *(const short8*)&lds[ab + aoff + i * 1024];
#pragma unroll
        for (int j = 0; j < 4; ++j) bfr[j] = *(const short8*)&lds[bb + boff[j]];

#pragma unroll
        for (int i = 0; i < 4; ++i)
#pragma unroll
            for (int j = 0; j < 4; ++j)
                acc[i][j] = __builtin_amdgcn_mfma_f32_16x16x32_bf16(af[i], bfr[j], acc[i][j], 0, 0, 0);

        if (t + 1 < NSTEPS) __syncthreads();
        cur = nxt;
    }

    // ---- epilogue: C/D col = lane&15, row = (lane>>4)*4 + r ----
    const int colb = n0 + wn + lm;
    const int rowb = m0 + wm + (kb_l << 2);
#pragma unroll
    for (int j = 0; j < 4; ++j) {
        const int col = colb + j * 16;
        const float bias_f = bias[col];
#pragma unroll
        for (int i = 0; i < 4; ++i) {
            const int row = rowb + i * 16;
#pragma unroll
            for (int r = 0; r < 4; ++r) {
                out[(size_t)(row + r) * N_DIM + col] = acc[i][j][r] + bias_f;
            }
        }
    }
}

extern "C" void kernel_launch(void* const* d_in, const int* in_sizes, int n_in,
                              void* d_out, int out_size, void* d_ws, size_t ws_size,
                              hipStream_t stream) {
    const float* x    = (const float*)d_in[0];
    const int* qw     = (const int*)d_in[1];
    const int* qz     = (const int*)d_in[2];
    const float* sc   = (const float*)d_in[3];
    const float* bi   = (const float*)d_in[4];
    float* out        = (float*)d_out;

    const int M = in_sizes[0] / K_DIM;                 // 8192
    const size_t xb_bytes = (size_t)M * K_DIM * 2;
    dim3 grid(N_DIM / BN, M / BM);                     // (86, 64)

    if (ws_size >= xb_bytes) {
        unsigned short* xb = (unsigned short*)d_ws;
        const int n8 = (int)((size_t)M * K_DIM / 8);
        cvt_x<<<2048, 256, 0, stream>>>(x, xb, n8);
        awq_gemm4<true><<<grid, 256, 0, stream>>>(x, xb, qw, qz, sc, bi, out);
    } else {
        awq_gemm4<false><<<grid, 256, 0, stream>>>(x, nullptr, qw, qz, sc, bi, out);
    }
}

// Round 8
// 1098.092 us; speedup vs baseline: 1.5050x; 1.0299x over previous
//
#include <hip/hip_runtime.h>
#include <hip/hip_fp16.h>
#include <stdint.h>

typedef __attribute__((ext_vector_type(8))) _Float16 half8;
typedef __attribute__((ext_vector_type(2))) _Float16 half2v;
typedef __attribute__((ext_vector_type(8))) short short8;
typedef __attribute__((ext_vector_type(4))) float floatx4;
typedef __attribute__((ext_vector_type(2))) float float2v;

#define K_DIM 4096
#define N_DIM 11008
#define NQ_DIM 1376
#define BK 32
#define NSTEPS 128
#define BM 128
#define BN 128
#define ABUF 8192
#define BBASE 16384
#define BBUF 8192

__device__ __forceinline__ uint32_t pkh(float a, float b) {
    half2v h; h[0] = (_Float16)a; h[1] = (_Float16)b;
    union { half2v h; uint32_t u; } c; c.h = h; return c.u;
}
__device__ __forceinline__ half2v u2h(uint32_t u) {
    union { uint32_t u; half2v h; } c; c.u = u; return c.h;
}
__device__ __forceinline__ uint32_t h2u(half2v h) {
    union { half2v h; uint32_t u; } c; c.h = h; return c.u;
}

// ---- pass 0: x f32 -> f16 into workspace ----
__global__ __launch_bounds__(256)
void cvt_x(const float* __restrict__ x, unsigned short* __restrict__ xb, int n8) {
    int i = blockIdx.x * 256 + threadIdx.x;
    const int stride = gridDim.x * 256;
    for (; i < n8; i += stride) {
        floatx4 a = *(const floatx4*)(x + (size_t)i * 8);
        floatx4 b = *(const floatx4*)(x + (size_t)i * 8 + 4);
        union { short8 v; uint32_t u[4]; } o;
        o.u[0] = pkh(a[0], a[1]);
        o.u[1] = pkh(a[2], a[3]);
        o.u[2] = pkh(b[0], b[1]);
        o.u[3] = pkh(b[2], b[3]);
        *(short8*)(xb + (size_t)i * 8) = o.v;
    }
}

// ---- fused AWQ GEMM: BM=128 x BN=128, BK=32, 256 threads (4 waves, 2M x 2N) ----
// LDS: A buf0 [0,8192), A buf1 [8192,16384)   : [kb=4][row=128][8k] f16, addr kb*2048+row*16
//      B buf0 [16384,24576), B buf1 [24576,32768): 16B blocks blk = kb*128 + swz(col)
// K-loop unrolled 2x so all buffer bases are compile-time immediates; 1 barrier per K-step.
template <bool PRECVT>
__global__ __launch_bounds__(256, 3)
void awq_gemm5(const float* __restrict__ xf,
               const unsigned short* __restrict__ xb,
               const int* __restrict__ qweight,
               const int* __restrict__ qzeros,
               const float* __restrict__ scales,
               const float* __restrict__ bias,
               float* __restrict__ out)
{
    __shared__ char lds[32768] __attribute__((aligned(128)));

    const int tid  = threadIdx.x;
    const int lane = tid & 63;
    const int wid  = tid >> 6;

    const int n0 = blockIdx.x * BN;
    const int m0 = blockIdx.y * BM;

    // ---- A staging: wave wid stages kb=wid (rows via lanes, 16B = full 8-k slice) ----
    const unsigned short* agl0 = xb + (size_t)(m0 + lane) * K_DIM + wid * 8;
    const unsigned short* agl1 = xb + (size_t)(m0 + 64 + lane) * K_DIM + wid * 8;
    // fallback (f32 x): thread owns row tid>>1, k-half tid&1 (16 floats -> kb 2h, 2h+1)
    const float* aptr = xf + (size_t)(m0 + (tid >> 1)) * K_DIM + (tid & 1) * 16;
    const int awr = ((tid & 1) * 2) * 2048 + (tid >> 1) * 16;

    // ---- B dequant mapping: thread owns k-pair (k_local, +1) x 8 logical cols ----
    const int nq      = tid & 15;
    const int k_local = (tid >> 4) * 2;
    const int kb_w    = k_local >> 3;
    const int k8      = k_local & 7;
    const int nq7     = nq & 7;
    const int* qp0 = qweight + blockIdx.x * 16 + nq + (size_t)k_local * NQ_DIM;
    const int* qp1 = qp0 + NQ_DIM;
    const int* zp  = qzeros + blockIdx.x * 16 + nq;
    const float* sp = scales + n0 + nq * 8;
    int baddr[8];
#pragma unroll
    for (int j = 0; j < 8; ++j)
        baddr[j] = BBASE + (kb_w * 128 + nq * 8 + (j ^ nq7)) * 16 + k8 * 2;

    // ---- fragment read offsets ----
    const int wm = (wid >> 1) * 64;
    const int wn = (wid & 1) * 64;
    const int lm = lane & 15;
    const int kb_l = lane >> 4;
    const int aoff = kb_l * 2048 + (wm + lm) * 16;   // + i*256
    int boff[4];
#pragma unroll
    for (int j = 0; j < 4; ++j) {
        int blk = kb_l * 128 + wn + j * 16 + lm;
        blk ^= (blk >> 3) & 7;
        boff[j] = BBASE + blk * 16;
    }

    floatx4 acc[4][4];
#pragma unroll
    for (int i = 0; i < 4; ++i)
#pragma unroll
        for (int j = 0; j < 4; ++j)
            acc[i][j] = (floatx4){0.f, 0.f, 0.f, 0.f};

    half2v zt[4], st[4];
    uint32_t q0, q1;

    auto stage_a = [&](int abase) {
        if constexpr (PRECVT) {
            __builtin_amdgcn_global_load_lds(
                (const __attribute__((address_space(1))) void*)agl0,
                (__attribute__((address_space(3))) void*)(&lds[abase + wid * 2048]), 16, 0, 0);
            __builtin_amdgcn_global_load_lds(
                (const __attribute__((address_space(1))) void*)agl1,
                (__attribute__((address_space(3))) void*)(&lds[abase + wid * 2048 + 1024]), 16, 0, 0);
            agl0 += BK; agl1 += BK;
        } else {
            floatx4 a0 = *(const floatx4*)(aptr + 0);
            floatx4 a1 = *(const floatx4*)(aptr + 4);
            floatx4 a2 = *(const floatx4*)(aptr + 8);
            floatx4 a3 = *(const floatx4*)(aptr + 12);
            aptr += BK;
            union { short8 v; uint32_t u[4]; } o0, o1;
            o0.u[0] = pkh(a0[0], a0[1]); o0.u[1] = pkh(a0[2], a0[3]);
            o0.u[2] = pkh(a1[0], a1[1]); o0.u[3] = pkh(a1[2], a1[3]);
            o1.u[0] = pkh(a2[0], a2[1]); o1.u[1] = pkh(a2[2], a2[3]);
            o1.u[2] = pkh(a3[0], a3[1]); o1.u[3] = pkh(a3[2], a3[3]);
            *(short8*)&lds[abase + awr]        = o0.v;
            *(short8*)&lds[abase + awr + 2048] = o1.v;
        }
    };
    auto load_q = [&]() {
        q0 = (uint32_t)*qp0;
        q1 = (uint32_t)*qp1;
        qp0 += (size_t)BK * NQ_DIM;
        qp1 += (size_t)BK * NQ_DIM;
    };
    auto refresh = [&]() {
        const uint32_t zw = (uint32_t)*zp;
        zp += NQ_DIM;
#pragma unroll
        for (int l = 0; l < 4; ++l) {
            zt[l] = u2h(((zw >> (4 * l)) & 0x000F000Fu) | 0x64006400u);  // (1024+z_2l, 1024+z_2l+1)
            float2v s2 = *(const float2v*)(sp + 2 * l);
            half2v sh; sh[0] = (_Float16)s2[0]; sh[1] = (_Float16)s2[1];
            st[l] = sh;
        }
        sp += N_DIM;
    };
    auto deq_store = [&](int off) {
#pragma unroll
        for (int l = 0; l < 4; ++l) {
            // packed (1024+nib) for logical cols (2l, 2l+1): shifts 4l and 4l+16
            uint32_t t0 = ((q0 >> (4 * l)) & 0x000F000Fu) | 0x64006400u;
            uint32_t t1 = ((q1 >> (4 * l)) & 0x000F000Fu) | 0x64006400u;
            half2v w0 = (u2h(t0) - zt[l]) * st[l];   // exact int sub, then fp16 mul
            half2v w1 = (u2h(t1) - zt[l]) * st[l];
            uint32_t p0 = h2u(w0), p1 = h2u(w1);
            // transpose n-pairs -> k-pairs
            uint32_t de = (p0 & 0xFFFFu) | (p1 << 16);          // col 2l:   (k, k+1)
            uint32_t dd = (p0 >> 16) | (p1 & 0xFFFF0000u);      // col 2l+1: (k, k+1)
            *(uint32_t*)&lds[baddr[2 * l]     + off] = de;
            *(uint32_t*)&lds[baddr[2 * l + 1] + off] = dd;
        }
    };
    auto compute = [&](int ab, int bb) {
        half8 af[4], bfr[4];
#pragma unroll
        for (int i = 0; i < 4; ++i) af[i] = *(const half8*)&lds[ab + aoff + i * 256];
#pragma unroll
        for (int j = 0; j < 4; ++j) bfr[j] = *(const half8*)&lds[bb + boff[j]];
#pragma unroll
        for (int i = 0; i < 4; ++i)
#pragma unroll
            for (int j = 0; j < 4; ++j)
                acc[i][j] = __builtin_amdgcn_mfma_f32_16x16x32_f16(af[i], bfr[j], acc[i][j], 0, 0, 0);
    };

    // ---- prologue ----
    stage_a(0);          // tile 0 -> A buf0
    load_q();            // q(0)
    refresh();           // g = 0
    deq_store(0);        // B(0) -> buf0
    load_q();            // q(1)
    __syncthreads();

    // ---- main loop, 2 K-steps per iteration ----
    for (int t = 0; t < NSTEPS; t += 2) {
        // phase 0: prep step t+1 into buf1; compute step t from buf0
        stage_a(ABUF);
        deq_store(BBUF);                     // consumes q(t+1)
        if (t + 2 < NSTEPS) load_q();        // q(t+2)
        compute(0, 0);
        __syncthreads();
        // phase 1: prep step t+2 into buf0; compute step t+1 from buf1
        if (t + 2 < NSTEPS) {
            stage_a(0);
            if (((t + 2) & 3) == 0) refresh();
            deq_store(0);                    // consumes q(t+2)
            if (t + 3 < NSTEPS) load_q();    // q(t+3)
        }
        compute(ABUF, BBUF);
        __syncthreads();
    }

    // ---- epilogue: C/D col = lane&15, row = (lane>>4)*4 + r ----
    const int colb = n0 + wn + lm;
    const int rowb = m0 + wm + (kb_l << 2);
#pragma unroll
    for (int j = 0; j < 4; ++j) {
        const int col = colb + j * 16;
        const float bias_f = bias[col];
#pragma unroll
        for (int i = 0; i < 4; ++i) {
            const int row = rowb + i * 16;
#pragma unroll
            for (int r = 0; r < 4; ++r) {
                out[(size_t)(row + r) * N_DIM + col] = acc[i][j][r] + bias_f;
            }
        }
    }
}

extern "C" void kernel_launch(void* const* d_in, const int* in_sizes, int n_in,
                              void* d_out, int out_size, void* d_ws, size_t ws_size,
                              hipStream_t stream) {
    const float* x    = (const float*)d_in[0];
    const int* qw     = (const int*)d_in[1];
    const int* qz     = (const int*)d_in[2];
    const float* sc   = (const float*)d_in[3];
    const float* bi   = (const float*)d_in[4];
    float* out        = (float*)d_out;

    const int M = in_sizes[0] / K_DIM;                 // 8192
    const size_t xb_bytes = (size_t)M * K_DIM * 2;
    dim3 grid(N_DIM / BN, M / BM);                     // (86, 64)

    if (ws_size >= xb_bytes) {
        unsigned short* xb = (unsigned short*)d_ws;
        const int n8 = (int)((size_t)M * K_DIM / 8);
        cvt_x<<<2048, 256, 0, stream>>>(x, xb, n8);
        awq_gemm5<true><<<grid, 256, 0, stream>>>(x, xb, qw, qz, sc, bi, out);
    } else {
        awq_gemm5<false><<<grid, 256, 0, stream>>>(x, nullptr, qw, qz, sc, bi, out);
    }
}